// Round 2
// baseline (177.781 us; speedup 1.0000x reference)
//
#include <hip/hip_runtime.h>
#include <hip/hip_cooperative_groups.h>
#include <math.h>

namespace cg = cooperative_groups;

#define OUT_F      4096
#define IN_F       4096
#define NUM_CHUNKS 16384
#define CHUNK_SIZE 1024
#define D_ALPHA    64
#define HIDDEN     256
#define TOKENS     256

typedef __attribute__((ext_vector_type(8))) __bf16 bf16x8;
typedef __attribute__((ext_vector_type(4))) __bf16 bf16x4;
typedef __attribute__((ext_vector_type(4))) float f32x4;

__device__ __forceinline__ void gl2lds16(const void* g, void* l) {
    __builtin_amdgcn_global_load_lds(
        (const __attribute__((address_space(1))) void*)g,
        (__attribute__((address_space(3))) void*)l,
        16, 0, 0);
}

__device__ __forceinline__ float gelu_erf(float v) {
    return 0.5f * v * (1.0f + erff(v * 0.70710678118654752f));
}

// Single cooperative kernel, grid = 512 x 256 (>=2 blocks/CU resident).
// Phase A (prep):
//   all blocks       : H 64x64 tiles -- b<256: tile b ; b>=256: 256+3*(b-256)+{0,1,2}
//   blocks [0,256)   : Y 32x32 tile (K=1024), Y = xr @ w2 -> bf16
//   blocks [256,512) : xb2[t] = dot(x[t], tile(b2)), t = b-256
// grid.sync()
// Phase B: out 32(m) x 64(n) tile per block = Ycat @ Hflat^T + bias + xb2
__global__ __launch_bounds__(256) void fused_kernel(
    const float* __restrict__ cb, const float* __restrict__ w1,
    const float* __restrict__ b1, const float* __restrict__ x,
    const float* __restrict__ b2, const float* __restrict__ w2,
    const float* __restrict__ bias,
    __bf16* __restrict__ H, __bf16* __restrict__ Y,
    float* __restrict__ xb2, float* __restrict__ out)
{
    __shared__ __align__(16) char smem[24576];
    const int b    = blockIdx.x;
    const int tid  = threadIdx.x;
    const int wave = tid >> 6, lane = tid & 63;
    const int fr   = lane & 15, fq = lane >> 4;

    // ================= Phase A1: H tiles =================
    {
        __bf16* sA = (__bf16*)smem;              // [64][72] bf16, 9216 B
        __bf16* sB = (__bf16*)(smem + 9216);     // [64][72]
        const int nt   = (b < 256) ? 1 : 3;
        const int base = (b < 256) ? b : 256 + (b - 256) * 3;
        const int wm = (wave & 1) * 32, wn = (wave >> 1) * 32;
        for (int t = 0; t < nt; ++t) {
            const int tile = base + t;
            const int by = tile >> 2, bx = tile & 3;
            const float4* cb4 = reinterpret_cast<const float4*>(cb) + (size_t)by * 1024;
            const float4* w14 = reinterpret_cast<const float4*>(w1) + (size_t)bx * 1024;
#pragma unroll
            for (int q = 0; q < 4; ++q) {
                const int idx = q * 256 + tid, row = idx >> 4, c = idx & 15;
                float4 va = cb4[idx], vb = w14[idx];
                bf16x4 oa, ob;
                oa.x=(__bf16)va.x; oa.y=(__bf16)va.y; oa.z=(__bf16)va.z; oa.w=(__bf16)va.w;
                ob.x=(__bf16)vb.x; ob.y=(__bf16)vb.y; ob.z=(__bf16)vb.z; ob.w=(__bf16)vb.w;
                *reinterpret_cast<bf16x4*>(sA + row * 72 + c * 4) = oa;
                *reinterpret_cast<bf16x4*>(sB + row * 72 + c * 4) = ob;
            }
            __syncthreads();
            f32x4 acc[2][2] = {};
            bf16x8 af[2], bv[2];
#pragma unroll
            for (int u = 0; u < 2; ++u) {
#pragma unroll
                for (int i = 0; i < 2; ++i) {
                    af[i] = *reinterpret_cast<const bf16x8*>(
                        sA + (wm + i * 16 + fr) * 72 + u * 32 + fq * 8);
                    bv[i] = *reinterpret_cast<const bf16x8*>(
                        sB + (wn + i * 16 + fr) * 72 + u * 32 + fq * 8);
                }
#pragma unroll
                for (int i = 0; i < 2; ++i)
#pragma unroll
                    for (int j = 0; j < 2; ++j)
                        acc[i][j] = __builtin_amdgcn_mfma_f32_16x16x32_bf16(
                            af[i], bv[j], acc[i][j], 0, 0, 0);
            }
#pragma unroll
            for (int j = 0; j < 2; ++j) {
                const int col = bx * 64 + wn + j * 16 + fr;
                const float bb = b1[col];
#pragma unroll
                for (int i = 0; i < 2; ++i) {
                    const int rbase = by * 64 + wm + i * 16 + fq * 4;
#pragma unroll
                    for (int r = 0; r < 4; ++r)
                        H[(size_t)(rbase + r) * 256 + col] =
                            (__bf16)gelu_erf(acc[i][j][r] + bb);
                }
            }
            __syncthreads();
        }
    }

    // ================= Phase A2: Y tile / xb2 =================
    if (b < 256) {
        // Y = xr(1024x1024) @ w2(1024x256), 32x32 tile, BK=64, stride-72 LDS
        __bf16* sA = (__bf16*)smem;              // [32][72]
        __bf16* sB = (__bf16*)(smem + 4608);     // [32][72]
        const int m0 = (b >> 3) * 32, n0 = (b & 7) * 32;
        const int wm = (wave & 1) * 16, wn = (wave >> 1) * 16;
        const float4* xv  = reinterpret_cast<const float4*>(x);
        const float4* w2v = reinterpret_cast<const float4*>(w2);
        f32x4 acc = {};
        for (int k0 = 0; k0 < 1024; k0 += 64) {
#pragma unroll
            for (int q = 0; q < 2; ++q) {
                const int idx = q * 256 + tid;
                const int row = idx >> 4, c = idx & 15;
                float4 v = xv[(size_t)(m0 + row) * 256 + (k0 >> 2) + c];
                bf16x4 o;
                o.x=(__bf16)v.x; o.y=(__bf16)v.y; o.z=(__bf16)v.z; o.w=(__bf16)v.w;
                *reinterpret_cast<bf16x4*>(sA + row * 72 + c * 4) = o;
            }
#pragma unroll
            for (int q = 0; q < 2; ++q) {
                const int idx = q * 256 + tid;
                const int kk = idx >> 3, c = idx & 7;
                float4 v = w2v[(size_t)(k0 + kk) * 64 + (n0 >> 2) + c];
                sB[(c * 4 + 0) * 72 + kk] = (__bf16)v.x;
                sB[(c * 4 + 1) * 72 + kk] = (__bf16)v.y;
                sB[(c * 4 + 2) * 72 + kk] = (__bf16)v.z;
                sB[(c * 4 + 3) * 72 + kk] = (__bf16)v.w;
            }
            __syncthreads();
#pragma unroll
            for (int u = 0; u < 2; ++u) {
                bf16x8 af = *reinterpret_cast<const bf16x8*>(
                    sA + (wm + fr) * 72 + u * 32 + fq * 8);
                bf16x8 bv = *reinterpret_cast<const bf16x8*>(
                    sB + (wn + fr) * 72 + u * 32 + fq * 8);
                acc = __builtin_amdgcn_mfma_f32_16x16x32_bf16(af, bv, acc, 0, 0, 0);
            }
            __syncthreads();
        }
#pragma unroll
        for (int r = 0; r < 4; ++r)
            Y[(size_t)(m0 + wm + fq * 4 + r) * 256 + n0 + wn + fr] = (__bf16)acc[r];
    } else {
        // xb2[t] = dot(x[t], tile(b2))
        float* ws_ = (float*)smem;
        const int t = b - 256;
        const float4* xr  = reinterpret_cast<const float4*>(x + (size_t)t * IN_F);
        const float4* b24 = reinterpret_cast<const float4*>(b2);
        float acc = 0.0f;
#pragma unroll
        for (int ii = 0; ii < 4; ++ii) {
            const int idx = ii * 256 + tid;
            float4 v = xr[idx];
            float4 bb = b24[idx & 255];
            acc += v.x * bb.x + v.y * bb.y + v.z * bb.z + v.w * bb.w;
        }
#pragma unroll
        for (int off = 32; off > 0; off >>= 1) acc += __shfl_down(acc, off, 64);
        if ((tid & 63) == 0) ws_[tid >> 6] = acc;
        __syncthreads();
        if (tid == 0) xb2[t] = ws_[0] + ws_[1] + ws_[2] + ws_[3];
        __syncthreads();
    }

    // ================= grid-wide barrier =================
    cg::this_grid().sync();

    // ================= Phase B: out tile 32x64 =================
    {
        __bf16* sA2 = (__bf16*)smem;             // [32][128] 8 KB
        __bf16* sB2 = (__bf16*)(smem + 8192);    // [64][128] 16 KB
        const __bf16* A = Y;                     // Ycat [256][1024] flat
        const __bf16* B = H;                     // Hflat [4096][1024] flat
        const int m0 = (b >> 6) * 32;            // 8 m-tiles
        const int n0 = (b & 63) * 64;            // 64 n-tiles
        const int wm = (wave & 1) * 16;
        const int wn = (wave >> 1) * 32;
        f32x4 acc[2] = {};
        for (int k0 = 0; k0 < 1024; k0 += 128) {
#pragma unroll
            for (int cc = 0; cc < 2; ++cc) {
                const int flat = cc * 2048 + tid * 8;
                gl2lds16(A + (size_t)(m0 + (flat >> 7)) * 1024 + k0 + (flat & 127),
                         sA2 + flat);
            }
#pragma unroll
            for (int cc = 0; cc < 4; ++cc) {
                const int flat = cc * 2048 + tid * 8;
                gl2lds16(B + (size_t)(n0 + (flat >> 7)) * 1024 + k0 + (flat & 127),
                         sB2 + flat);
            }
            __syncthreads();
#pragma unroll
            for (int u = 0; u < 4; ++u) {
                bf16x8 af = *reinterpret_cast<const bf16x8*>(
                    sA2 + (wm + fr) * 128 + u * 32 + fq * 8);
#pragma unroll
                for (int j = 0; j < 2; ++j) {
                    bf16x8 bv = *reinterpret_cast<const bf16x8*>(
                        sB2 + (wn + j * 16 + fr) * 128 + u * 32 + fq * 8);
                    acc[j] = __builtin_amdgcn_mfma_f32_16x16x32_bf16(
                        af, bv, acc[j], 0, 0, 0);
                }
            }
            __syncthreads();
        }
#pragma unroll
        for (int j = 0; j < 2; ++j) {
            const int col = n0 + wn + j * 16 + fr;
            const float bvs = bias[col];
            const int rbase = m0 + wm + fq * 4;
#pragma unroll
            for (int r = 0; r < 4; ++r)
                out[(size_t)(rbase + r) * 4096 + col] =
                    acc[j][r] + bvs + xb2[rbase + r];
        }
    }
}

extern "C" void kernel_launch(void* const* d_in, const int* in_sizes, int n_in,
                              void* d_out, int out_size, void* d_ws, size_t ws_size,
                              hipStream_t stream) {
    const float* x        = (const float*)d_in[0];
    const float* codebook = (const float*)d_in[1];
    const float* w1       = (const float*)d_in[2];
    const float* b1       = (const float*)d_in[3];
    const float* w2       = (const float*)d_in[4];
    const float* b2       = (const float*)d_in[5];
    const float* bias     = (const float*)d_in[6];
    float* out = (float*)d_out;

    // ws layout:
    //   H    bf16 16384x256   8 MB   @ 0
    //   Y    bf16 1024x256   .5 MB   @ 8 MB
    //   xb2  fp32 256         1 KB   @ 8.5 MB
    char* ws = (char*)d_ws;
    __bf16* H   = (__bf16*)(ws);
    __bf16* Y   = (__bf16*)(ws + (8u << 20));
    float*  xb2 = (float*)(ws + (8u << 20) + (512u << 10));

    void* kargs[] = {(void*)&codebook, (void*)&w1, (void*)&b1, (void*)&x,
                     (void*)&b2, (void*)&w2, (void*)&bias,
                     (void*)&H, (void*)&Y, (void*)&xb2, (void*)&out};
    hipLaunchCooperativeKernel(fused_kernel, dim3(512), dim3(256),
                               kargs, 0, stream);
}

// Round 3
// 97.507 us; speedup vs baseline: 1.8233x; 1.8233x over previous
//
#include <hip/hip_runtime.h>
#include <math.h>

#define OUT_F      4096
#define IN_F       4096
#define NUM_CHUNKS 16384
#define CHUNK_SIZE 1024
#define D_ALPHA    64
#define HIDDEN     256
#define TOKENS     256

typedef __attribute__((ext_vector_type(8))) __bf16 bf16x8;
typedef __attribute__((ext_vector_type(4))) __bf16 bf16x4;
typedef __attribute__((ext_vector_type(4))) float f32x4;

__device__ __forceinline__ void gl2lds16(const void* g, void* l) {
    __builtin_amdgcn_global_load_lds(
        (const __attribute__((address_space(1))) void*)g,
        (__attribute__((address_space(3))) void*)l,
        16, 0, 0);
}

// ============ KA: fused prep + Y (verified round-1 structure) ==============
// blocks [0,1024)     : H = gelu(codebook @ w1^T + b1) via MFMA, 64x64 tile
// blocks [1024,1152)  : Y = xr(1024x1024) @ w2 (f32->bf16 staged, w2
//                       transposed in LDS), 32x64 tiles
// blocks [1152,1408)  : xb2[t] = dot(x[t], tile(b2))
__global__ __launch_bounds__(256) void prep_kernel(
    const float* __restrict__ cb, const float* __restrict__ w1,
    const float* __restrict__ b1, const float* __restrict__ x,
    const float* __restrict__ b2, const float* __restrict__ w2,
    __bf16* __restrict__ H, __bf16* __restrict__ Y,
    float* __restrict__ xb2) {
    __shared__ char smem[16384];
    const int b   = blockIdx.x;
    const int tid = threadIdx.x;

    if (b < 1024) {
        const int by = b >> 2;
        const int bx = b & 3;
        const int c0 = by * 64, h0 = bx * 64;
        __bf16* sA = (__bf16*)smem;            // 64x64 bf16 (8 KB)
        __bf16* sB = (__bf16*)(smem + 8192);   // 64x64 bf16
        const float4* cb4 = reinterpret_cast<const float4*>(cb) + (size_t)by * 1024;
        const float4* w14 = reinterpret_cast<const float4*>(w1) + (size_t)bx * 1024;
#pragma unroll
        for (int q = 0; q < 4; ++q) {
            const int idx = q * 256 + tid;
            float4 va = cb4[idx];
            float4 vb = w14[idx];
            bf16x4 oa, ob;
            oa.x = (__bf16)va.x; oa.y = (__bf16)va.y; oa.z = (__bf16)va.z; oa.w = (__bf16)va.w;
            ob.x = (__bf16)vb.x; ob.y = (__bf16)vb.y; ob.z = (__bf16)vb.z; ob.w = (__bf16)vb.w;
            *reinterpret_cast<bf16x4*>(sA + idx * 4) = oa;
            *reinterpret_cast<bf16x4*>(sB + idx * 4) = ob;
        }
        __syncthreads();
        const int wave = tid >> 6, lane = tid & 63;
        const int wm = (wave & 1) * 32, wn = (wave >> 1) * 32;
        const int fr = lane & 15, fq = lane >> 4;
        f32x4 acc[2][2] = {};
        bf16x8 af[2][2], bv[2][2];
#pragma unroll
        for (int i = 0; i < 2; ++i)
#pragma unroll
            for (int u = 0; u < 2; ++u) {
                af[i][u] = *reinterpret_cast<const bf16x8*>(
                    sA + (wm + i * 16 + fr) * 64 + u * 32 + fq * 8);
                bv[i][u] = *reinterpret_cast<const bf16x8*>(
                    sB + (wn + i * 16 + fr) * 64 + u * 32 + fq * 8);
            }
#pragma unroll
        for (int u = 0; u < 2; ++u)
#pragma unroll
            for (int i = 0; i < 2; ++i)
#pragma unroll
                for (int j = 0; j < 2; ++j)
                    acc[i][j] = __builtin_amdgcn_mfma_f32_16x16x32_bf16(
                        af[i][u], bv[j][u], acc[i][j], 0, 0, 0);
#pragma unroll
        for (int j = 0; j < 2; ++j) {
            const int col = h0 + wn + j * 16 + fr;
            const float bb = b1[col];
#pragma unroll
            for (int i = 0; i < 2; ++i) {
                const int rbase = c0 + wm + i * 16 + fq * 4;
#pragma unroll
                for (int r = 0; r < 4; ++r) {
                    float v = acc[i][j][r] + bb;
                    float g = 0.5f * v * (1.0f + erff(v * 0.70710678118654752f));
                    H[(size_t)(rbase + r) * 256 + col] = (__bf16)g;
                }
            }
        }
    } else if (b < 1152) {
        // ---- Y = xr @ w2 : M=1024, N=256, K=1024; 32x64 tile, BK=64 ------
        const int yb = b - 1024;
        const int m0 = (yb >> 2) * 32;     // 32 m-tiles
        const int n0 = (yb & 3) * 64;      // 4 n-tiles
        __bf16* sA = (__bf16*)smem;                  // 32 x 72 (4608 B)
        __bf16* sB = (__bf16*)(smem + 32 * 72 * 2);  // 64 x 72 (9216 B)
        const int wave = tid >> 6, lane = tid & 63;
        const int fr = lane & 15, fq = lane >> 4;
        const int wn = wave * 16;          // 4 waves x 16 cols = 64 cols
        const float4* xv  = reinterpret_cast<const float4*>(x);
        const float4* w2v = reinterpret_cast<const float4*>(w2);
        f32x4 acc[2] = {};

        for (int k0 = 0; k0 < 1024; k0 += 64) {
#pragma unroll
            for (int q = 0; q < 2; ++q) {
                const int idx = q * 256 + tid;       // [0,512)
                const int row = idx >> 4, c = idx & 15;
                float4 v = xv[(size_t)(m0 + row) * 256 + (k0 >> 2) + c];
                bf16x4 o;
                o.x = (__bf16)v.x; o.y = (__bf16)v.y; o.z = (__bf16)v.z; o.w = (__bf16)v.w;
                *reinterpret_cast<bf16x4*>(sA + row * 72 + c * 4) = o;
            }
#pragma unroll
            for (int q = 0; q < 4; ++q) {
                const int idx = q * 256 + tid;       // [0,1024)
                const int kk = idx >> 4, c = idx & 15;
                float4 v = w2v[(size_t)(k0 + kk) * 64 + (n0 >> 2) + c];
                sB[(c * 4 + 0) * 72 + kk] = (__bf16)v.x;
                sB[(c * 4 + 1) * 72 + kk] = (__bf16)v.y;
                sB[(c * 4 + 2) * 72 + kk] = (__bf16)v.z;
                sB[(c * 4 + 3) * 72 + kk] = (__bf16)v.w;
            }
            __syncthreads();
#pragma unroll
            for (int u = 0; u < 2; ++u) {
                bf16x8 bv = *reinterpret_cast<const bf16x8*>(
                    sB + (wn + fr) * 72 + u * 32 + fq * 8);
#pragma unroll
                for (int i = 0; i < 2; ++i) {
                    bf16x8 af = *reinterpret_cast<const bf16x8*>(
                        sA + (i * 16 + fr) * 72 + u * 32 + fq * 8);
                    acc[i] = __builtin_amdgcn_mfma_f32_16x16x32_bf16(
                        af, bv, acc[i], 0, 0, 0);
                }
            }
            __syncthreads();
        }
#pragma unroll
        for (int i = 0; i < 2; ++i) {
            const int rbase = m0 + i * 16 + fq * 4;
            const int col = n0 + wn + fr;
#pragma unroll
            for (int r = 0; r < 4; ++r)
                Y[(size_t)(rbase + r) * 256 + col] = (__bf16)acc[i][r];
        }
    } else {
        // ---- xb2[t] = dot(x[t], tile(b2)) ----
        float* ws_ = (float*)smem;
        const int t = b - 1152;
        const float4* xr  = reinterpret_cast<const float4*>(x + (size_t)t * IN_F);
        const float4* b24 = reinterpret_cast<const float4*>(b2);
        float acc = 0.0f;
#pragma unroll
        for (int ii = 0; ii < 4; ++ii) {
            const int idx = ii * 256 + tid;
            float4 v = xr[idx];
            float4 bb = b24[idx & 255];
            acc += v.x * bb.x + v.y * bb.y + v.z * bb.z + v.w * bb.w;
        }
#pragma unroll
        for (int off = 32; off > 0; off >>= 1) acc += __shfl_down(acc, off, 64);
        if ((tid & 63) == 0) ws_[tid >> 6] = acc;
        __syncthreads();
        if (tid == 0) xb2[t] = ws_[0] + ws_[1] + ws_[2] + ws_[3];
    }
}

// ============ KB: out-GEMM 32x64 tile, BK=128, XOR-swizzled LDS =============
// C[256][4096] = A[256][1024] @ B[4096][1024]^T + bias[col] + rowterm[row]
// 512 blocks (2/CU). Swizzle (rule #21): LDS dest linear (global_load_lds),
// global SOURCE col pre-XORed with (row&7)<<3 (16B bank-shift per row),
// ds_read applies the same XOR -> 2-way residual aliasing (free).
__global__ __launch_bounds__(256) void gemm_out(
    const __bf16* __restrict__ A, const __bf16* __restrict__ B,
    const float* __restrict__ bias, const float* __restrict__ rowterm,
    float* __restrict__ C) {
    __shared__ __bf16 sA[32 * 128];   //  8 KB
    __shared__ __bf16 sB[64 * 128];   // 16 KB
    const int tid = threadIdx.x;
    const int m0 = blockIdx.y * 32;
    const int n0 = blockIdx.x * 64;
    const int wave = tid >> 6, lane = tid & 63;
    const int wm = (wave & 1) * 16, wn = (wave >> 1) * 32;
    const int fr = lane & 15, fq = lane >> 4;
    const int sw = (fr & 7) << 3;     // read-side XOR (row&7 == fr&7)

    f32x4 acc[2] = {};

    for (int k0 = 0; k0 < 1024; k0 += 128) {
#pragma unroll
        for (int cc = 0; cc < 2; ++cc) {
            const int flat = cc * 2048 + tid * 8;
            const int row = flat >> 7, col = flat & 127;
            gl2lds16(A + (size_t)(m0 + row) * 1024 + k0 + (col ^ ((row & 7) << 3)),
                     sA + flat);
        }
#pragma unroll
        for (int cc = 0; cc < 4; ++cc) {
            const int flat = cc * 2048 + tid * 8;
            const int row = flat >> 7, col = flat & 127;
            gl2lds16(B + (size_t)(n0 + row) * 1024 + k0 + (col ^ ((row & 7) << 3)),
                     sB + flat);
        }
        __syncthreads();

#pragma unroll
        for (int u = 0; u < 4; ++u) {
            bf16x8 af = *reinterpret_cast<const bf16x8*>(
                sA + (wm + fr) * 128 + ((u * 32 + fq * 8) ^ sw));
#pragma unroll
            for (int j = 0; j < 2; ++j) {
                bf16x8 bv = *reinterpret_cast<const bf16x8*>(
                    sB + (wn + j * 16 + fr) * 128 + ((u * 32 + fq * 8) ^ sw));
                acc[j] = __builtin_amdgcn_mfma_f32_16x16x32_bf16(
                    af, bv, acc[j], 0, 0, 0);
            }
        }
        __syncthreads();
    }

#pragma unroll
    for (int j = 0; j < 2; ++j) {
        const int col = n0 + wn + j * 16 + fr;
        const float bvs = bias[col];
        const int rbase = m0 + wm + fq * 4;
#pragma unroll
        for (int r = 0; r < 4; ++r)
            C[(size_t)(rbase + r) * 4096 + col] =
                acc[j][r] + bvs + rowterm[rbase + r];
    }
}

extern "C" void kernel_launch(void* const* d_in, const int* in_sizes, int n_in,
                              void* d_out, int out_size, void* d_ws, size_t ws_size,
                              hipStream_t stream) {
    const float* x        = (const float*)d_in[0];
    const float* codebook = (const float*)d_in[1];
    const float* w1       = (const float*)d_in[2];
    const float* b1       = (const float*)d_in[3];
    const float* w2       = (const float*)d_in[4];
    const float* b2       = (const float*)d_in[5];
    const float* bias     = (const float*)d_in[6];
    float* out = (float*)d_out;

    // ws layout:
    //   H    bf16 16384x256   8 MB   @ 0
    //   Y    bf16 1024x256   .5 MB   @ 8 MB
    //   xb2  fp32 256         1 KB   @ 8.5 MB
    char* ws = (char*)d_ws;
    __bf16* H   = (__bf16*)(ws);
    __bf16* Y   = (__bf16*)(ws + (8u << 20));
    float*  xb2 = (float*)(ws + (8u << 20) + (512u << 10));

    // KA: H (1024 blocks) + Y gemm (128 blocks) + xb2 rowdot (256 blocks)
    prep_kernel<<<1408, 256, 0, stream>>>(codebook, w1, b1, x, b2, w2,
                                          H, Y, xb2);

    // KB: out = Ycat(256x1024) @ Hflat(4096x1024)^T + bias[col] + xb2[row]
    {
        dim3 grid(OUT_F / 64, TOKENS / 32, 1);   // 64 x 8 = 512 blocks
        gemm_out<<<grid, 256, 0, stream>>>(Y, H, bias, xb2, out);
    }
}

// Round 4
// 93.303 us; speedup vs baseline: 1.9054x; 1.0451x over previous
//
#include <hip/hip_runtime.h>
#include <math.h>

#define OUT_F      4096
#define IN_F       4096
#define NUM_CHUNKS 16384
#define CHUNK_SIZE 1024
#define D_ALPHA    64
#define HIDDEN     256
#define TOKENS     256

typedef __attribute__((ext_vector_type(8))) __bf16 bf16x8;
typedef __attribute__((ext_vector_type(4))) __bf16 bf16x4;
typedef __attribute__((ext_vector_type(4))) float f32x4;

__device__ __forceinline__ void gl2lds16(const void* g, void* l) {
    __builtin_amdgcn_global_load_lds(
        (const __attribute__((address_space(1))) void*)g,
        (__attribute__((address_space(3))) void*)l,
        16, 0, 0);
}

// ============ KA: fused prep + Y ===========================================
// blocks [0,128)      : Y = xr(1024x1024) @ w2, 32x64 tile, K-pipelined
//                       (dispatched FIRST: longest serial chain)
// blocks [128,1152)   : H = gelu(codebook @ w1^T + b1), 64x64 MFMA tile
// blocks [1152,1408)  : xb2[t] = dot(x[t], tile(b2))
__global__ __launch_bounds__(256) void prep_kernel(
    const float* __restrict__ cb, const float* __restrict__ w1,
    const float* __restrict__ b1, const float* __restrict__ x,
    const float* __restrict__ b2, const float* __restrict__ w2,
    __bf16* __restrict__ H, __bf16* __restrict__ Y,
    float* __restrict__ xb2) {
    __shared__ char smem[16384];
    const int b   = blockIdx.x;
    const int tid = threadIdx.x;

    if (b < 128) {
        // ---- Y = xr @ w2 : M=1024, N=256, K=1024; 32x64 tile, BK=64 ------
        // T14 pipeline: prefetch K-tile k+1 into regs while MFMA consumes k.
        const int m0 = (b >> 2) * 32;      // 32 m-tiles
        const int n0 = (b & 3) * 64;       // 4 n-tiles
        __bf16* sA = (__bf16*)smem;                  // 32 x 72 (4608 B)
        __bf16* sB = (__bf16*)(smem + 32 * 72 * 2);  // 64 x 72 (9216 B)
        const int wave = tid >> 6, lane = tid & 63;
        const int fr = lane & 15, fq = lane >> 4;
        const int wn = wave * 16;          // 4 waves x 16 cols = 64 cols
        const float4* xv  = reinterpret_cast<const float4*>(x);
        const float4* w2v = reinterpret_cast<const float4*>(w2);
        f32x4 acc[2] = {};
        float4 pa[2], pb[4];

        // prefetch K-tile 0
#pragma unroll
        for (int q = 0; q < 2; ++q) {
            const int idx = q * 256 + tid;
            pa[q] = xv[(size_t)(m0 + (idx >> 4)) * 256 + (idx & 15)];
        }
#pragma unroll
        for (int q = 0; q < 4; ++q) {
            const int idx = q * 256 + tid;
            pb[q] = w2v[(size_t)(idx >> 4) * 64 + (n0 >> 2) + (idx & 15)];
        }

        for (int kt = 0; kt < 16; ++kt) {
            // regs -> LDS (convert + transpose-scatter for B)
#pragma unroll
            for (int q = 0; q < 2; ++q) {
                const int idx = q * 256 + tid;
                const int row = idx >> 4, c = idx & 15;
                bf16x4 o;
                o.x = (__bf16)pa[q].x; o.y = (__bf16)pa[q].y;
                o.z = (__bf16)pa[q].z; o.w = (__bf16)pa[q].w;
                *reinterpret_cast<bf16x4*>(sA + row * 72 + c * 4) = o;
            }
#pragma unroll
            for (int q = 0; q < 4; ++q) {
                const int idx = q * 256 + tid;
                const int kk = idx >> 4, c = idx & 15;
                sB[(c * 4 + 0) * 72 + kk] = (__bf16)pb[q].x;
                sB[(c * 4 + 1) * 72 + kk] = (__bf16)pb[q].y;
                sB[(c * 4 + 2) * 72 + kk] = (__bf16)pb[q].z;
                sB[(c * 4 + 3) * 72 + kk] = (__bf16)pb[q].w;
            }
            __syncthreads();

            // issue prefetch for kt+1 (latency hides under MFMA + barrier)
            if (kt < 15) {
                const int k0n = (kt + 1) * 64;
#pragma unroll
                for (int q = 0; q < 2; ++q) {
                    const int idx = q * 256 + tid;
                    pa[q] = xv[(size_t)(m0 + (idx >> 4)) * 256 + (k0n >> 2) + (idx & 15)];
                }
#pragma unroll
                for (int q = 0; q < 4; ++q) {
                    const int idx = q * 256 + tid;
                    pb[q] = w2v[(size_t)(k0n + (idx >> 4)) * 64 + (n0 >> 2) + (idx & 15)];
                }
            }

#pragma unroll
            for (int u = 0; u < 2; ++u) {
                bf16x8 bv = *reinterpret_cast<const bf16x8*>(
                    sB + (wn + fr) * 72 + u * 32 + fq * 8);
#pragma unroll
                for (int i = 0; i < 2; ++i) {
                    bf16x8 af = *reinterpret_cast<const bf16x8*>(
                        sA + (i * 16 + fr) * 72 + u * 32 + fq * 8);
                    acc[i] = __builtin_amdgcn_mfma_f32_16x16x32_bf16(
                        af, bv, acc[i], 0, 0, 0);
                }
            }
            __syncthreads();
        }
#pragma unroll
        for (int i = 0; i < 2; ++i) {
            const int rbase = m0 + i * 16 + fq * 4;
            const int col = n0 + wn + fr;
#pragma unroll
            for (int r = 0; r < 4; ++r)
                Y[(size_t)(rbase + r) * 256 + col] = (__bf16)acc[i][r];
        }
    } else if (b < 1152) {
        const int tile = b - 128;
        const int by = tile >> 2;
        const int bx = tile & 3;
        const int c0 = by * 64, h0 = bx * 64;
        __bf16* sA = (__bf16*)smem;            // 64x64 bf16 (8 KB)
        __bf16* sB = (__bf16*)(smem + 8192);   // 64x64 bf16
        const float4* cb4 = reinterpret_cast<const float4*>(cb) + (size_t)by * 1024;
        const float4* w14 = reinterpret_cast<const float4*>(w1) + (size_t)bx * 1024;
#pragma unroll
        for (int q = 0; q < 4; ++q) {
            const int idx = q * 256 + tid;
            float4 va = cb4[idx];
            float4 vb = w14[idx];
            bf16x4 oa, ob;
            oa.x = (__bf16)va.x; oa.y = (__bf16)va.y; oa.z = (__bf16)va.z; oa.w = (__bf16)va.w;
            ob.x = (__bf16)vb.x; ob.y = (__bf16)vb.y; ob.z = (__bf16)vb.z; ob.w = (__bf16)vb.w;
            *reinterpret_cast<bf16x4*>(sA + idx * 4) = oa;
            *reinterpret_cast<bf16x4*>(sB + idx * 4) = ob;
        }
        __syncthreads();
        const int wave = tid >> 6, lane = tid & 63;
        const int wm = (wave & 1) * 32, wn = (wave >> 1) * 32;
        const int fr = lane & 15, fq = lane >> 4;
        f32x4 acc[2][2] = {};
        bf16x8 af[2][2], bv[2][2];
#pragma unroll
        for (int i = 0; i < 2; ++i)
#pragma unroll
            for (int u = 0; u < 2; ++u) {
                af[i][u] = *reinterpret_cast<const bf16x8*>(
                    sA + (wm + i * 16 + fr) * 64 + u * 32 + fq * 8);
                bv[i][u] = *reinterpret_cast<const bf16x8*>(
                    sB + (wn + i * 16 + fr) * 64 + u * 32 + fq * 8);
            }
#pragma unroll
        for (int u = 0; u < 2; ++u)
#pragma unroll
            for (int i = 0; i < 2; ++i)
#pragma unroll
                for (int j = 0; j < 2; ++j)
                    acc[i][j] = __builtin_amdgcn_mfma_f32_16x16x32_bf16(
                        af[i][u], bv[j][u], acc[i][j], 0, 0, 0);
#pragma unroll
        for (int j = 0; j < 2; ++j) {
            const int col = h0 + wn + j * 16 + fr;
            const float bb = b1[col];
#pragma unroll
            for (int i = 0; i < 2; ++i) {
                const int rbase = c0 + wm + i * 16 + fq * 4;
#pragma unroll
                for (int r = 0; r < 4; ++r) {
                    float v = acc[i][j][r] + bb;
                    float g = 0.5f * v * (1.0f + erff(v * 0.70710678118654752f));
                    H[(size_t)(rbase + r) * 256 + col] = (__bf16)g;
                }
            }
        }
    } else {
        // ---- xb2[t] = dot(x[t], tile(b2)) ----
        float* ws_ = (float*)smem;
        const int t = b - 1152;
        const float4* xr  = reinterpret_cast<const float4*>(x + (size_t)t * IN_F);
        const float4* b24 = reinterpret_cast<const float4*>(b2);
        float acc = 0.0f;
#pragma unroll
        for (int ii = 0; ii < 4; ++ii) {
            const int idx = ii * 256 + tid;
            float4 v = xr[idx];
            float4 bb = b24[idx & 255];
            acc += v.x * bb.x + v.y * bb.y + v.z * bb.z + v.w * bb.w;
        }
#pragma unroll
        for (int off = 32; off > 0; off >>= 1) acc += __shfl_down(acc, off, 64);
        if ((tid & 63) == 0) ws_[tid >> 6] = acc;
        __syncthreads();
        if (tid == 0) xb2[t] = ws_[0] + ws_[1] + ws_[2] + ws_[3];
    }
}

// ============ KB: out-GEMM 32x64 tile, BK=128, XOR-swizzled LDS =============
// C[256][4096] = A[256][1024] @ B[4096][1024]^T + bias[col] + rowterm[row]
// 512 blocks (2/CU). Swizzle (rule #21): LDS dest linear (global_load_lds),
// global SOURCE col pre-XORed with (row&7)<<3 (16B bank-shift per row),
// ds_read applies the same XOR -> 2-way residual aliasing (free).
__global__ __launch_bounds__(256) void gemm_out(
    const __bf16* __restrict__ A, const __bf16* __restrict__ B,
    const float* __restrict__ bias, const float* __restrict__ rowterm,
    float* __restrict__ C) {
    __shared__ __bf16 sA[32 * 128];   //  8 KB
    __shared__ __bf16 sB[64 * 128];   // 16 KB
    const int tid = threadIdx.x;
    const int m0 = blockIdx.y * 32;
    const int n0 = blockIdx.x * 64;
    const int wave = tid >> 6, lane = tid & 63;
    const int wm = (wave & 1) * 16, wn = (wave >> 1) * 32;
    const int fr = lane & 15, fq = lane >> 4;
    const int sw = (fr & 7) << 3;     // read-side XOR (row&7 == fr&7)

    f32x4 acc[2] = {};

    for (int k0 = 0; k0 < 1024; k0 += 128) {
#pragma unroll
        for (int cc = 0; cc < 2; ++cc) {
            const int flat = cc * 2048 + tid * 8;
            const int row = flat >> 7, col = flat & 127;
            gl2lds16(A + (size_t)(m0 + row) * 1024 + k0 + (col ^ ((row & 7) << 3)),
                     sA + flat);
        }
#pragma unroll
        for (int cc = 0; cc < 4; ++cc) {
            const int flat = cc * 2048 + tid * 8;
            const int row = flat >> 7, col = flat & 127;
            gl2lds16(B + (size_t)(n0 + row) * 1024 + k0 + (col ^ ((row & 7) << 3)),
                     sB + flat);
        }
        __syncthreads();

#pragma unroll
        for (int u = 0; u < 4; ++u) {
            bf16x8 af = *reinterpret_cast<const bf16x8*>(
                sA + (wm + fr) * 128 + ((u * 32 + fq * 8) ^ sw));
#pragma unroll
            for (int j = 0; j < 2; ++j) {
                bf16x8 bv = *reinterpret_cast<const bf16x8*>(
                    sB + (wn + j * 16 + fr) * 128 + ((u * 32 + fq * 8) ^ sw));
                acc[j] = __builtin_amdgcn_mfma_f32_16x16x32_bf16(
                    af, bv, acc[j], 0, 0, 0);
            }
        }
        __syncthreads();
    }

#pragma unroll
    for (int j = 0; j < 2; ++j) {
        const int col = n0 + wn + j * 16 + fr;
        const float bvs = bias[col];
        const int rbase = m0 + wm + fq * 4;
#pragma unroll
        for (int r = 0; r < 4; ++r)
            C[(size_t)(rbase + r) * 4096 + col] =
                acc[j][r] + bvs + rowterm[rbase + r];
    }
}

extern "C" void kernel_launch(void* const* d_in, const int* in_sizes, int n_in,
                              void* d_out, int out_size, void* d_ws, size_t ws_size,
                              hipStream_t stream) {
    const float* x        = (const float*)d_in[0];
    const float* codebook = (const float*)d_in[1];
    const float* w1       = (const float*)d_in[2];
    const float* b1       = (const float*)d_in[3];
    const float* w2       = (const float*)d_in[4];
    const float* b2       = (const float*)d_in[5];
    const float* bias     = (const float*)d_in[6];
    float* out = (float*)d_out;

    // ws layout:
    //   H    bf16 16384x256   8 MB   @ 0
    //   Y    bf16 1024x256   .5 MB   @ 8 MB
    //   xb2  fp32 256         1 KB   @ 8.5 MB
    char* ws = (char*)d_ws;
    __bf16* H   = (__bf16*)(ws);
    __bf16* Y   = (__bf16*)(ws + (8u << 20));
    float*  xb2 = (float*)(ws + (8u << 20) + (512u << 10));

    // KA: Y gemm (128 blocks, first) + H (1024 blocks) + xb2 rowdot (256)
    prep_kernel<<<1408, 256, 0, stream>>>(codebook, w1, b1, x, b2, w2,
                                          H, Y, xb2);

    // KB: out = Ycat(256x1024) @ Hflat(4096x1024)^T + bias[col] + xb2[row]
    {
        dim3 grid(OUT_F / 64, TOKENS / 32, 1);   // 64 x 8 = 512 blocks
        gemm_out<<<grid, 256, 0, stream>>>(Y, H, bias, xb2, out);
    }
}